// Round 17
// baseline (290.869 us; speedup 1.0000x reference)
//
#include <hip/hip_runtime.h>

#define NN 50000
#define NE 800000
#define F  128
#define BN_EPS 1e-5f
#define R    8                        // atomic replicas
#define CAPR 16                       // per-replica per-node bucket capacity
#define CAP  (R * CAPR)               // 128 ints = 512B bucket row per node
#define EPT  4                        // edges per thread (atomic MLP)
#define NT   (NE / EPT)               // 200000 threads

// ---------------------------------------------------------------------------
// Kernel 1: fused degree-count + bucket-CSR fill, replicated atomics,
// EPT=4 edges/thread split-stride: 8 independent atomics in flight per
// thread before the first waitcnt (latency-bound -> Little's law fix).
// ---------------------------------------------------------------------------
__global__ __launch_bounds__(256) void k_count_fill_rep(const int* __restrict__ src,
                                                        const int* __restrict__ dst,
                                                        int* __restrict__ degout_rep,
                                                        int* __restrict__ cursor,
                                                        int* __restrict__ bucket) {
    int t = blockIdx.x * 256 + threadIdx.x;
    int rep = blockIdx.x & (R - 1);
    if (t >= NT) return;
    int s0 = src[t];           int d0 = dst[t];
    int s1 = src[t + NT];      int d1 = dst[t + NT];
    int s2 = src[t + 2 * NT];  int d2 = dst[t + 2 * NT];
    int s3 = src[t + 3 * NT];  int d3 = dst[t + 3 * NT];
    int* dr = degout_rep + rep * NN;
    int* cu = cursor + rep * NN;
    atomicAdd(&dr[s0], 1);
    atomicAdd(&dr[s1], 1);
    atomicAdd(&dr[s2], 1);
    atomicAdd(&dr[s3], 1);
    int p0 = atomicAdd(&cu[d0], 1);
    int p1 = atomicAdd(&cu[d1], 1);
    int p2 = atomicAdd(&cu[d2], 1);
    int p3 = atomicAdd(&cu[d3], 1);
    if (p0 < CAPR) bucket[(size_t)d0 * CAP + rep * CAPR + p0] = s0;
    if (p1 < CAPR) bucket[(size_t)d1 * CAP + rep * CAPR + p1] = s1;
    if (p2 < CAPR) bucket[(size_t)d2 * CAP + rep * CAPR + p2] = s2;
    if (p3 < CAPR) bucket[(size_t)d3 * CAP + rep * CAPR + p3] = s3;
}

// ---------------------------------------------------------------------------
// Kernel 2: reduce out-degree replicas -> inv_out floats (tiny)
// ---------------------------------------------------------------------------
__global__ __launch_bounds__(256) void k_invout(const int* __restrict__ degout_rep,
                                                float* __restrict__ inv_out) {
    int i = blockIdx.x * 256 + threadIdx.x;
    if (i < NN) {
        int t = 0;
        #pragma unroll
        for (int r = 0; r < R; ++r) t += degout_rep[r * NN + i];
        inv_out[i] = (t > 0) ? rsqrtf((float)t) : 0.0f;
    }
}

// ---------------------------------------------------------------------------
// Kernel 3: gather-SpMM from replicated bucket CSR, zero atomics.
// 32 lanes/node, float4/lane; flat j -> (rep, off) via predicated scan.
// ---------------------------------------------------------------------------
__global__ __launch_bounds__(256) void k_gather(const float4* __restrict__ feat4,
                                                const int* __restrict__ bucket,
                                                const int* __restrict__ cursor,
                                                const float* __restrict__ inv_out,
                                                float4* __restrict__ agg4) {
    int node = blockIdx.x * 8 + (threadIdx.x >> 5);
    int lane = threadIdx.x & 31;
    if (node >= NN) return;

    int cl = 0;
    if (lane < R) cl = min(cursor[lane * NN + node], CAPR);
    int c[R];
    int deg = 0;
    #pragma unroll
    for (int r = 0; r < R; ++r) { c[r] = __shfl(cl, r, 32); deg += c[r]; }

    const int* bkt = bucket + (size_t)node * CAP;
    float4 acc = make_float4(0.f, 0.f, 0.f, 0.f);

    for (int b = 0; b < deg; b += 32) {
        int n = min(32, deg - b);
        int sl = 0;
        float scl = 0.0f;
        if (lane < n) {
            int jj = b + lane;
            int rep = 0;
            #pragma unroll
            for (int r = 0; r < R - 1; ++r) {
                bool adv = (rep == r) && (jj >= c[r]);
                if (adv) { jj -= c[r]; rep = r + 1; }
            }
            sl  = bkt[rep * CAPR + jj];
            scl = inv_out[sl];
        }
        int j = 0;
        for (; j + 4 <= n; j += 4) {
            int s0 = __shfl(sl, j + 0, 32);
            int s1 = __shfl(sl, j + 1, 32);
            int s2 = __shfl(sl, j + 2, 32);
            int s3 = __shfl(sl, j + 3, 32);
            float c0 = __shfl(scl, j + 0, 32);
            float c1 = __shfl(scl, j + 1, 32);
            float c2 = __shfl(scl, j + 2, 32);
            float c3 = __shfl(scl, j + 3, 32);
            float4 v0 = feat4[(size_t)s0 * (F / 4) + lane];
            float4 v1 = feat4[(size_t)s1 * (F / 4) + lane];
            float4 v2 = feat4[(size_t)s2 * (F / 4) + lane];
            float4 v3 = feat4[(size_t)s3 * (F / 4) + lane];
            acc.x += v0.x * c0; acc.y += v0.y * c0; acc.z += v0.z * c0; acc.w += v0.w * c0;
            acc.x += v1.x * c1; acc.y += v1.y * c1; acc.z += v1.z * c1; acc.w += v1.w * c1;
            acc.x += v2.x * c2; acc.y += v2.y * c2; acc.z += v2.z * c2; acc.w += v2.w * c2;
            acc.x += v3.x * c3; acc.y += v3.y * c3; acc.z += v3.z * c3; acc.w += v3.w * c3;
        }
        for (; j < n; ++j) {
            int   s  = __shfl(sl, j, 32);
            float sc = __shfl(scl, j, 32);
            float4 v = feat4[(size_t)s * (F / 4) + lane];
            acc.x += v.x * sc; acc.y += v.y * sc;
            acc.z += v.z * sc; acc.w += v.w * sc;
        }
    }
    float si = (deg > 0) ? rsqrtf((float)deg) : 0.0f;
    acc.x *= si; acc.y *= si; acc.z *= si; acc.w *= si;
    agg4[(size_t)node * (F / 4) + lane] = acc;
}

// ---------------------------------------------------------------------------
// Kernel 4: fused  out = dropout(agg @ W + b)  + per-column sum/sumsq
// ---------------------------------------------------------------------------
__device__ __forceinline__ void fma4(float4& acc, float a, const float4& w) {
    acc.x += a * w.x; acc.y += a * w.y; acc.z += a * w.z; acc.w += a * w.w;
}

__global__ __launch_bounds__(128) void k_gemm(const float* __restrict__ agg,
                                              const float* __restrict__ W,
                                              const float* __restrict__ bias,
                                              const float* __restrict__ mask,
                                              float* __restrict__ out,
                                              float* __restrict__ colsum,
                                              float* __restrict__ colsumsq) {
    __shared__ float Wl[64 * F];     // 32 KB: one K-half of W
    __shared__ float s_sum[F];
    __shared__ float s_sq[F];

    int tid = threadIdx.x;           // 0..127
    const int cgrp = tid & 15;
    const int rgrp = tid >> 4;
    const int c0   = cgrp * 8;
    const int r0   = blockIdx.x * 64 + rgrp * 8;
    s_sum[tid] = 0.0f;
    s_sq[tid]  = 0.0f;

    const float4* agg4 = reinterpret_cast<const float4*>(agg);
    const float4* arow[8];
    #pragma unroll
    for (int i = 0; i < 8; ++i) {
        int r = r0 + i;
        arow[i] = agg4 + (size_t)((r < NN) ? r : 0) * (F / 4);
    }

    float4 acc[8][2];
    #pragma unroll
    for (int i = 0; i < 8; ++i) {
        acc[i][0] = make_float4(0.f, 0.f, 0.f, 0.f);
        acc[i][1] = make_float4(0.f, 0.f, 0.f, 0.f);
    }

    float4* Wl4w = reinterpret_cast<float4*>(Wl);
    const float4* Wl4 = reinterpret_cast<const float4*>(Wl);

    for (int half = 0; half < 2; ++half) {
        __syncthreads();
        const float4* Wg4 = reinterpret_cast<const float4*>(W + half * 64 * F);
        #pragma unroll
        for (int i = 0; i < 16; ++i)
            Wl4w[tid + i * 128] = Wg4[tid + i * 128];
        __syncthreads();

        #pragma unroll 2
        for (int k4 = 0; k4 < 16; ++k4) {
            float4 tv[8];
            #pragma unroll
            for (int i = 0; i < 8; ++i) tv[i] = arow[i][half * 16 + k4];
            #pragma unroll
            for (int kk = 0; kk < 4; ++kk) {
                const float4 w0 = Wl4[((k4 * 4 + kk) * F + c0) >> 2];
                const float4 w1 = Wl4[((k4 * 4 + kk) * F + c0 + 4) >> 2];
                #pragma unroll
                for (int i = 0; i < 8; ++i) {
                    float a = (&tv[i].x)[kk];
                    fma4(acc[i][0], a, w0);
                    fma4(acc[i][1], a, w1);
                }
            }
        }
    }

    float4 b0 = *reinterpret_cast<const float4*>(bias + c0);
    float4 b1 = *reinterpret_cast<const float4*>(bias + c0 + 4);
    float lsum[8] = {0, 0, 0, 0, 0, 0, 0, 0};
    float lsq[8]  = {0, 0, 0, 0, 0, 0, 0, 0};
    #pragma unroll
    for (int i = 0; i < 8; ++i) {
        int r = r0 + i;
        if (r < NN) {
            const float4* mrow = reinterpret_cast<const float4*>(mask + (size_t)r * F + c0);
            float4 m0 = mrow[0];
            float4 m1 = mrow[1];
            float4 o0, o1;
            o0.x = (acc[i][0].x + b0.x) * m0.x * 2.0f;
            o0.y = (acc[i][0].y + b0.y) * m0.y * 2.0f;
            o0.z = (acc[i][0].z + b0.z) * m0.z * 2.0f;
            o0.w = (acc[i][0].w + b0.w) * m0.w * 2.0f;
            o1.x = (acc[i][1].x + b1.x) * m1.x * 2.0f;
            o1.y = (acc[i][1].y + b1.y) * m1.y * 2.0f;
            o1.z = (acc[i][1].z + b1.z) * m1.z * 2.0f;
            o1.w = (acc[i][1].w + b1.w) * m1.w * 2.0f;
            float4* orow = reinterpret_cast<float4*>(out + (size_t)r * F + c0);
            orow[0] = o0;
            orow[1] = o1;
            lsum[0] += o0.x; lsq[0] += o0.x * o0.x;
            lsum[1] += o0.y; lsq[1] += o0.y * o0.y;
            lsum[2] += o0.z; lsq[2] += o0.z * o0.z;
            lsum[3] += o0.w; lsq[3] += o0.w * o0.w;
            lsum[4] += o1.x; lsq[4] += o1.x * o1.x;
            lsum[5] += o1.y; lsq[5] += o1.y * o1.y;
            lsum[6] += o1.z; lsq[6] += o1.z * o1.z;
            lsum[7] += o1.w; lsq[7] += o1.w * o1.w;
        }
    }
    #pragma unroll
    for (int j = 0; j < 8; ++j) {
        atomicAdd(&s_sum[c0 + j], lsum[j]);
        atomicAdd(&s_sq[c0 + j], lsq[j]);
    }
    __syncthreads();
    atomicAdd(&colsum[tid], s_sum[tid]);
    atomicAdd(&colsumsq[tid], s_sq[tid]);
}

// ---------------------------------------------------------------------------
// Kernel 5: BatchNorm finalize in place on d_out.
// ---------------------------------------------------------------------------
__global__ __launch_bounds__(256) void k_bn(float4* __restrict__ out4,
                                            const float* __restrict__ colsum,
                                            const float* __restrict__ colsumsq,
                                            const float* __restrict__ gamma,
                                            const float* __restrict__ beta) {
    __shared__ float ssc[F];
    __shared__ float ssh[F];
    int tid = threadIdx.x;
    if (tid < F) {
        float mean = colsum[tid] * (1.0f / NN);
        float var  = colsumsq[tid] * (1.0f / NN) - mean * mean;
        float sc   = rsqrtf(var + BN_EPS) * gamma[tid];
        ssc[tid] = sc;
        ssh[tid] = beta[tid] - mean * sc;
    }
    __syncthreads();
    int gid = blockIdx.x * 256 + tid;
    if (gid < NN * F / 4) {
        const float4 sc4 = reinterpret_cast<const float4*>(ssc)[gid & 31];
        const float4 sh4 = reinterpret_cast<const float4*>(ssh)[gid & 31];
        float4 v = out4[gid];
        v.x = v.x * sc4.x + sh4.x;
        v.y = v.y * sc4.y + sh4.y;
        v.z = v.z * sc4.z + sh4.z;
        v.w = v.w * sc4.w + sh4.w;
        out4[gid] = v;
    }
}

// ---------------------------------------------------------------------------
// launch
// ---------------------------------------------------------------------------
extern "C" void kernel_launch(void* const* d_in, const int* in_sizes, int n_in,
                              void* d_out, int out_size, void* d_ws, size_t ws_size,
                              hipStream_t stream) {
    const float* feat  = (const float*)d_in[0];
    const int*   src   = (const int*)d_in[1];
    const int*   dst   = (const int*)d_in[2];
    const float* W     = (const float*)d_in[3];
    const float* bias  = (const float*)d_in[4];
    const float* gamma = (const float*)d_in[5];
    const float* beta  = (const float*)d_in[6];
    const float* mask  = (const float*)d_in[7];
    float* out = (float*)d_out;

    // ws layout:
    // agg[NN*F] | bucket[NN*CAP] |
    // ZERO{ cursor[R*NN] | degout_rep[R*NN] | colsum[F] | colsumsq[F] } |
    // inv_out[NN]
    float* agg        = (float*)d_ws;
    int*   bucket     = (int*)(agg + (size_t)NN * F);
    int*   cursor     = bucket + (size_t)NN * CAP;
    int*   degout_rep = cursor + (size_t)R * NN;
    float* colsum     = (float*)(degout_rep + (size_t)R * NN);
    float* colsumsq   = colsum + F;
    float* inv_out    = colsumsq + F;

    hipMemsetAsync(cursor, 0, (2 * (size_t)R * NN + 2 * F) * sizeof(int), stream);

    k_count_fill_rep<<<(NT + 255) / 256, 256, 0, stream>>>(src, dst, degout_rep,
                                                           cursor, bucket);
    k_invout<<<(NN + 255) / 256, 256, 0, stream>>>(degout_rep, inv_out);
    k_gather<<<NN / 8, 256, 0, stream>>>((const float4*)feat, bucket, cursor,
                                         inv_out, (float4*)agg);
    k_gemm<<<(NN + 63) / 64, 128, 0, stream>>>(agg, W, bias, mask, out,
                                               colsum, colsumsq);
    k_bn<<<(NN * F / 4 + 255) / 256, 256, 0, stream>>>((float4*)out, colsum,
                                                       colsumsq, gamma, beta);
}

// Round 18
// 259.994 us; speedup vs baseline: 1.1188x; 1.1188x over previous
//
#include <hip/hip_runtime.h>

#define NN 50000
#define NE 800000
#define F  128
#define BN_EPS 1e-5f
#define R    8                        // edge chunks (= bucket replicas)
#define CAPR 16                       // per-chunk per-node bucket capacity
#define CAP  (R * CAPR)               // 128 ints = 512B bucket row per node
#define NPB  1024                     // nodes per range-block
#define NRANGE 49                     // ceil(NN/NPB)
#define CHUNK  (NE / R)               // 100000 edges per chunk
#define CHUNK4 (CHUNK / 4)            // 25000 int4 per chunk

// ---------------------------------------------------------------------------
// Kernel 1: CSR build with ZERO global atomics. Block (chunk c, range r)
// scans chunk c of dst[] (int4), keeps nodes in [r*NPB, r*NPB+NPB), takes
// slot positions from an LDS cursor, writes bucket[d*CAP + c*CAPR + pos].
// Second pass histograms src[] for out-degrees. Dense stores of per-chunk
// cursor/degree replace the old global-atomic count_fill AND its memset.
// ---------------------------------------------------------------------------
__global__ __launch_bounds__(1024) void k_build(const int4* __restrict__ src4,
                                                const int4* __restrict__ dst4,
                                                const int* __restrict__ src,
                                                int* __restrict__ degout_rep,
                                                int* __restrict__ cursor,
                                                int* __restrict__ bucket) {
    int c = blockIdx.x & (R - 1);
    int r = blockIdx.x >> 3;
    int base = r * NPB;
    int tid = threadIdx.x;
    __shared__ int lcur[NPB];
    __shared__ int lhist[NPB];
    lcur[tid] = 0;
    lhist[tid] = 0;
    __syncthreads();

    const int q0 = c * CHUNK4;
    // pass 1: dst scan -> bucket fill (LDS cursor gives unique positions)
    for (int q = q0 + tid; q < q0 + CHUNK4; q += NPB) {
        int4 dv = dst4[q];
        int e = q * 4;
        #pragma unroll
        for (int k = 0; k < 4; ++k) {
            int d = (&dv.x)[k];
            unsigned rel = (unsigned)(d - base);
            if (rel < NPB) {
                int pos = atomicAdd(&lcur[rel], 1);   // LDS atomic
                if (pos < CAPR) {
                    int s = src[e + k];
                    bucket[(size_t)d * CAP + c * CAPR + pos] = s;
                }
            }
        }
    }
    // pass 2: src scan -> out-degree histogram
    for (int q = q0 + tid; q < q0 + CHUNK4; q += NPB) {
        int4 sv = src4[q];
        #pragma unroll
        for (int k = 0; k < 4; ++k) {
            int s = (&sv.x)[k];
            unsigned rel = (unsigned)(s - base);
            if (rel < NPB) atomicAdd(&lhist[rel], 1); // LDS atomic
        }
    }
    __syncthreads();
    int node = base + tid;
    if (node < NN) {
        cursor[c * NN + node] = lcur[tid];
        degout_rep[c * NN + node] = lhist[tid];
    }
}

// ---------------------------------------------------------------------------
// Kernel 2: reduce out-degree replicas -> inv_out floats (tiny)
// ---------------------------------------------------------------------------
__global__ __launch_bounds__(256) void k_invout(const int* __restrict__ degout_rep,
                                                float* __restrict__ inv_out) {
    int i = blockIdx.x * 256 + threadIdx.x;
    if (i < NN) {
        int t = 0;
        #pragma unroll
        for (int r = 0; r < R; ++r) t += degout_rep[r * NN + i];
        inv_out[i] = (t > 0) ? rsqrtf((float)t) : 0.0f;
    }
}

// ---------------------------------------------------------------------------
// Kernel 3: gather-SpMM from chunked bucket CSR, zero atomics.
// 32 lanes/node, float4/lane; flat j -> (chunk, off) via predicated scan.
// ---------------------------------------------------------------------------
__global__ __launch_bounds__(256) void k_gather(const float4* __restrict__ feat4,
                                                const int* __restrict__ bucket,
                                                const int* __restrict__ cursor,
                                                const float* __restrict__ inv_out,
                                                float4* __restrict__ agg4) {
    int node = blockIdx.x * 8 + (threadIdx.x >> 5);
    int lane = threadIdx.x & 31;
    if (node >= NN) return;

    int cl = 0;
    if (lane < R) cl = min(cursor[lane * NN + node], CAPR);
    int c[R];
    int deg = 0;
    #pragma unroll
    for (int r = 0; r < R; ++r) { c[r] = __shfl(cl, r, 32); deg += c[r]; }

    const int* bkt = bucket + (size_t)node * CAP;
    float4 acc = make_float4(0.f, 0.f, 0.f, 0.f);

    for (int b = 0; b < deg; b += 32) {
        int n = min(32, deg - b);
        int sl = 0;
        float scl = 0.0f;
        if (lane < n) {
            int jj = b + lane;
            int rep = 0;
            #pragma unroll
            for (int r = 0; r < R - 1; ++r) {
                bool adv = (rep == r) && (jj >= c[r]);
                if (adv) { jj -= c[r]; rep = r + 1; }
            }
            sl  = bkt[rep * CAPR + jj];
            scl = inv_out[sl];
        }
        int j = 0;
        for (; j + 4 <= n; j += 4) {
            int s0 = __shfl(sl, j + 0, 32);
            int s1 = __shfl(sl, j + 1, 32);
            int s2 = __shfl(sl, j + 2, 32);
            int s3 = __shfl(sl, j + 3, 32);
            float c0 = __shfl(scl, j + 0, 32);
            float c1 = __shfl(scl, j + 1, 32);
            float c2 = __shfl(scl, j + 2, 32);
            float c3 = __shfl(scl, j + 3, 32);
            float4 v0 = feat4[(size_t)s0 * (F / 4) + lane];
            float4 v1 = feat4[(size_t)s1 * (F / 4) + lane];
            float4 v2 = feat4[(size_t)s2 * (F / 4) + lane];
            float4 v3 = feat4[(size_t)s3 * (F / 4) + lane];
            acc.x += v0.x * c0; acc.y += v0.y * c0; acc.z += v0.z * c0; acc.w += v0.w * c0;
            acc.x += v1.x * c1; acc.y += v1.y * c1; acc.z += v1.z * c1; acc.w += v1.w * c1;
            acc.x += v2.x * c2; acc.y += v2.y * c2; acc.z += v2.z * c2; acc.w += v2.w * c2;
            acc.x += v3.x * c3; acc.y += v3.y * c3; acc.z += v3.z * c3; acc.w += v3.w * c3;
        }
        for (; j < n; ++j) {
            int   s  = __shfl(sl, j, 32);
            float sc = __shfl(scl, j, 32);
            float4 v = feat4[(size_t)s * (F / 4) + lane];
            acc.x += v.x * sc; acc.y += v.y * sc;
            acc.z += v.z * sc; acc.w += v.w * sc;
        }
    }
    float si = (deg > 0) ? rsqrtf((float)deg) : 0.0f;
    acc.x *= si; acc.y *= si; acc.z *= si; acc.w *= si;
    agg4[(size_t)node * (F / 4) + lane] = acc;
}

// ---------------------------------------------------------------------------
// Kernel 4: fused  out = dropout(agg @ W + b)  + per-column sum/sumsq
// ---------------------------------------------------------------------------
__device__ __forceinline__ void fma4(float4& acc, float a, const float4& w) {
    acc.x += a * w.x; acc.y += a * w.y; acc.z += a * w.z; acc.w += a * w.w;
}

__global__ __launch_bounds__(128) void k_gemm(const float* __restrict__ agg,
                                              const float* __restrict__ W,
                                              const float* __restrict__ bias,
                                              const float* __restrict__ mask,
                                              float* __restrict__ out,
                                              float* __restrict__ colsum,
                                              float* __restrict__ colsumsq) {
    __shared__ float Wl[64 * F];     // 32 KB: one K-half of W
    __shared__ float s_sum[F];
    __shared__ float s_sq[F];

    int tid = threadIdx.x;           // 0..127
    const int cgrp = tid & 15;
    const int rgrp = tid >> 4;
    const int c0   = cgrp * 8;
    const int r0   = blockIdx.x * 64 + rgrp * 8;
    s_sum[tid] = 0.0f;
    s_sq[tid]  = 0.0f;

    const float4* agg4 = reinterpret_cast<const float4*>(agg);
    const float4* arow[8];
    #pragma unroll
    for (int i = 0; i < 8; ++i) {
        int r = r0 + i;
        arow[i] = agg4 + (size_t)((r < NN) ? r : 0) * (F / 4);
    }

    float4 acc[8][2];
    #pragma unroll
    for (int i = 0; i < 8; ++i) {
        acc[i][0] = make_float4(0.f, 0.f, 0.f, 0.f);
        acc[i][1] = make_float4(0.f, 0.f, 0.f, 0.f);
    }

    float4* Wl4w = reinterpret_cast<float4*>(Wl);
    const float4* Wl4 = reinterpret_cast<const float4*>(Wl);

    for (int half = 0; half < 2; ++half) {
        __syncthreads();
        const float4* Wg4 = reinterpret_cast<const float4*>(W + half * 64 * F);
        #pragma unroll
        for (int i = 0; i < 16; ++i)
            Wl4w[tid + i * 128] = Wg4[tid + i * 128];
        __syncthreads();

        #pragma unroll 2
        for (int k4 = 0; k4 < 16; ++k4) {
            float4 tv[8];
            #pragma unroll
            for (int i = 0; i < 8; ++i) tv[i] = arow[i][half * 16 + k4];
            #pragma unroll
            for (int kk = 0; kk < 4; ++kk) {
                const float4 w0 = Wl4[((k4 * 4 + kk) * F + c0) >> 2];
                const float4 w1 = Wl4[((k4 * 4 + kk) * F + c0 + 4) >> 2];
                #pragma unroll
                for (int i = 0; i < 8; ++i) {
                    float a = (&tv[i].x)[kk];
                    fma4(acc[i][0], a, w0);
                    fma4(acc[i][1], a, w1);
                }
            }
        }
    }

    float4 b0 = *reinterpret_cast<const float4*>(bias + c0);
    float4 b1 = *reinterpret_cast<const float4*>(bias + c0 + 4);
    float lsum[8] = {0, 0, 0, 0, 0, 0, 0, 0};
    float lsq[8]  = {0, 0, 0, 0, 0, 0, 0, 0};
    #pragma unroll
    for (int i = 0; i < 8; ++i) {
        int r = r0 + i;
        if (r < NN) {
            const float4* mrow = reinterpret_cast<const float4*>(mask + (size_t)r * F + c0);
            float4 m0 = mrow[0];
            float4 m1 = mrow[1];
            float4 o0, o1;
            o0.x = (acc[i][0].x + b0.x) * m0.x * 2.0f;
            o0.y = (acc[i][0].y + b0.y) * m0.y * 2.0f;
            o0.z = (acc[i][0].z + b0.z) * m0.z * 2.0f;
            o0.w = (acc[i][0].w + b0.w) * m0.w * 2.0f;
            o1.x = (acc[i][1].x + b1.x) * m1.x * 2.0f;
            o1.y = (acc[i][1].y + b1.y) * m1.y * 2.0f;
            o1.z = (acc[i][1].z + b1.z) * m1.z * 2.0f;
            o1.w = (acc[i][1].w + b1.w) * m1.w * 2.0f;
            float4* orow = reinterpret_cast<float4*>(out + (size_t)r * F + c0);
            orow[0] = o0;
            orow[1] = o1;
            lsum[0] += o0.x; lsq[0] += o0.x * o0.x;
            lsum[1] += o0.y; lsq[1] += o0.y * o0.y;
            lsum[2] += o0.z; lsq[2] += o0.z * o0.z;
            lsum[3] += o0.w; lsq[3] += o0.w * o0.w;
            lsum[4] += o1.x; lsq[4] += o1.x * o1.x;
            lsum[5] += o1.y; lsq[5] += o1.y * o1.y;
            lsum[6] += o1.z; lsq[6] += o1.z * o1.z;
            lsum[7] += o1.w; lsq[7] += o1.w * o1.w;
        }
    }
    #pragma unroll
    for (int j = 0; j < 8; ++j) {
        atomicAdd(&s_sum[c0 + j], lsum[j]);
        atomicAdd(&s_sq[c0 + j], lsq[j]);
    }
    __syncthreads();
    atomicAdd(&colsum[tid], s_sum[tid]);
    atomicAdd(&colsumsq[tid], s_sq[tid]);
}

// ---------------------------------------------------------------------------
// Kernel 5: BatchNorm finalize in place on d_out.
// ---------------------------------------------------------------------------
__global__ __launch_bounds__(256) void k_bn(float4* __restrict__ out4,
                                            const float* __restrict__ colsum,
                                            const float* __restrict__ colsumsq,
                                            const float* __restrict__ gamma,
                                            const float* __restrict__ beta) {
    __shared__ float ssc[F];
    __shared__ float ssh[F];
    int tid = threadIdx.x;
    if (tid < F) {
        float mean = colsum[tid] * (1.0f / NN);
        float var  = colsumsq[tid] * (1.0f / NN) - mean * mean;
        float sc   = rsqrtf(var + BN_EPS) * gamma[tid];
        ssc[tid] = sc;
        ssh[tid] = beta[tid] - mean * sc;
    }
    __syncthreads();
    int gid = blockIdx.x * 256 + tid;
    if (gid < NN * F / 4) {
        const float4 sc4 = reinterpret_cast<const float4*>(ssc)[gid & 31];
        const float4 sh4 = reinterpret_cast<const float4*>(ssh)[gid & 31];
        float4 v = out4[gid];
        v.x = v.x * sc4.x + sh4.x;
        v.y = v.y * sc4.y + sh4.y;
        v.z = v.z * sc4.z + sh4.z;
        v.w = v.w * sc4.w + sh4.w;
        out4[gid] = v;
    }
}

// ---------------------------------------------------------------------------
// launch
// ---------------------------------------------------------------------------
extern "C" void kernel_launch(void* const* d_in, const int* in_sizes, int n_in,
                              void* d_out, int out_size, void* d_ws, size_t ws_size,
                              hipStream_t stream) {
    const float* feat  = (const float*)d_in[0];
    const int*   src   = (const int*)d_in[1];
    const int*   dst   = (const int*)d_in[2];
    const float* W     = (const float*)d_in[3];
    const float* bias  = (const float*)d_in[4];
    const float* gamma = (const float*)d_in[5];
    const float* beta  = (const float*)d_in[6];
    const float* mask  = (const float*)d_in[7];
    float* out = (float*)d_out;

    // ws layout:
    // agg[NN*F] | bucket[NN*CAP] | cursor[R*NN] | degout_rep[R*NN] |
    // ZERO{ colsum[F] | colsumsq[F] } | inv_out[NN]
    float* agg        = (float*)d_ws;
    int*   bucket     = (int*)(agg + (size_t)NN * F);
    int*   cursor     = bucket + (size_t)NN * CAP;
    int*   degout_rep = cursor + (size_t)R * NN;
    float* colsum     = (float*)(degout_rep + (size_t)R * NN);
    float* colsumsq   = colsum + F;
    float* inv_out    = colsumsq + F;

    hipMemsetAsync(colsum, 0, 2 * F * sizeof(float), stream);

    k_build<<<NRANGE * R, NPB, 0, stream>>>((const int4*)src, (const int4*)dst,
                                            src, degout_rep, cursor, bucket);
    k_invout<<<(NN + 255) / 256, 256, 0, stream>>>(degout_rep, inv_out);
    k_gather<<<NN / 8, 256, 0, stream>>>((const float4*)feat, bucket, cursor,
                                         inv_out, (float4*)agg);
    k_gemm<<<(NN + 63) / 64, 128, 0, stream>>>(agg, W, bias, mask, out,
                                               colsum, colsumsq);
    k_bn<<<(NN * F / 4 + 255) / 256, 256, 0, stream>>>((float4*)out, colsum,
                                                       colsumsq, gamma, beta);
}